// Round 2
// baseline (621.274 us; speedup 1.0000x reference)
//
#include <hip/hip_runtime.h>
#include <math.h>

#define BATCH 8
#define T 1024
#define DM 512
#define NH 8
#define CHD 64
#define NROW 8192            // BATCH*T
#define NEG_INF (-INFINITY)
#define SENT (-1.0e30f)      // finite stand-in for -inf in d_out (harness can't diff -inf vs -inf)

// ---------------------------------------------------------------- n_valid
__global__ __launch_bounds__(256) void k_nvalid(const int* __restrict__ tokens,
                                                int* __restrict__ nv) {
  int b = blockIdx.x;
  int t = threadIdx.x;
  int cnt = 0;
  for (int i = t; i < T; i += 256) cnt += (tokens[b * T + i] != 0) ? 1 : 0;
  __shared__ int s[256];
  s[t] = cnt;
  __syncthreads();
  for (int st = 128; st > 0; st >>= 1) {
    if (t < st) s[t] += s[t + st];
    __syncthreads();
  }
  if (t == 0) nv[b] = s[0];
}

// ---------------------------------------------------------------- helpers
__device__ __forceinline__ void fma16(float (&acc)[4][4], float4 a, float4 b4) {
  acc[0][0] += a.x * b4.x; acc[0][1] += a.x * b4.y; acc[0][2] += a.x * b4.z; acc[0][3] += a.x * b4.w;
  acc[1][0] += a.y * b4.x; acc[1][1] += a.y * b4.y; acc[1][2] += a.y * b4.z; acc[1][3] += a.y * b4.w;
  acc[2][0] += a.z * b4.x; acc[2][1] += a.z * b4.y; acc[2][2] += a.z * b4.z; acc[2][3] += a.z * b4.w;
  acc[3][0] += a.w * b4.x; acc[3][1] += a.w * b4.y; acc[3][2] += a.w * b4.z; acc[3][3] += a.w * b4.w;
}

// load a 64x64 fp32 tile (row stride 512 floats) transposed into LDS [c][row]
__device__ __forceinline__ void load_tile64(float (*dst)[68],
                                            const float* __restrict__ base,
                                            int tid) {
  const int r = tid >> 2;
  const int c0 = (tid & 3) * 16;
  const float* src = base + (size_t)r * 512 + c0;
#pragma unroll
  for (int u = 0; u < 4; ++u) {
    float4 v = *(const float4*)(src + 4 * u);
    dst[c0 + 4 * u + 0][r] = v.x;
    dst[c0 + 4 * u + 1][r] = v.y;
    dst[c0 + 4 * u + 2][r] = v.z;
    dst[c0 + 4 * u + 3][r] = v.w;
  }
}

// ---------------------------------------------------------------- fused q/k GEMM
__global__ __launch_bounds__(256) void k_qk_gemm(
    const float* __restrict__ feat, const float* __restrict__ pos,
    const float* __restrict__ Wq, const float* __restrict__ bq,
    const float* __restrict__ Wk, const float* __restrict__ bk,
    float* __restrict__ qout, float* __restrict__ kout) {
  const int nt = blockIdx.x;  // 0..15
  const int mt = blockIdx.y;  // 0..127
  const int m0 = mt * 64, n0 = nt * 64;
  const int tid = threadIdx.x;
  const int tx = tid & 15, ty = tid >> 4;
  __shared__ float As[16][68];
  __shared__ float Bs[16][68];
  float acc[4][4] = {};
  const int lr = tid >> 2;       // 0..63
  const int lk = (tid & 3) * 4;  // 0,4,8,12
  const float* Arow_f = feat + (size_t)(m0 + lr) * 512;
  const float* Arow_p = pos + (size_t)(m0 + lr) * 512;
  const int nrow = n0 + lr;
  const float* Brow = (nrow < 512) ? (Wq + (size_t)nrow * 1024)
                                   : (Wk + (size_t)(nrow - 512) * 1024);
  for (int k0 = 0; k0 < 1024; k0 += 16) {
    const int k = k0 + lk;
    float4 av = (k0 < 512) ? *(const float4*)(Arow_f + k)
                           : *(const float4*)(Arow_p + (k - 512));
    float4 bv = *(const float4*)(Brow + k);
    __syncthreads();
    As[lk + 0][lr] = av.x; As[lk + 1][lr] = av.y; As[lk + 2][lr] = av.z; As[lk + 3][lr] = av.w;
    Bs[lk + 0][lr] = bv.x; Bs[lk + 1][lr] = bv.y; Bs[lk + 2][lr] = bv.z; Bs[lk + 3][lr] = bv.w;
    __syncthreads();
#pragma unroll
    for (int c = 0; c < 16; ++c) {
      float4 a = *(const float4*)&As[c][ty * 4];
      float4 b4 = *(const float4*)&Bs[c][tx * 4];
      fma16(acc, a, b4);
    }
  }
  const int nc = n0 + tx * 4;
  float4 bias = (nc < 512) ? *(const float4*)(bq + nc)
                           : *(const float4*)(bk + (nc - 512));
  float* obase = (nc < 512) ? (qout + nc) : (kout + (nc - 512));
#pragma unroll
  for (int r = 0; r < 4; ++r) {
    const int m = m0 + ty * 4 + r;
    float4 v;
    v.x = acc[r][0] + bias.x;
    v.y = acc[r][1] + bias.y;
    v.z = acc[r][2] + bias.z;
    v.w = acc[r][3] + bias.w;
    *(float4*)(obase + (size_t)m * 512) = v;
  }
}

// ---------------------------------------------------------------- gates
__global__ __launch_bounds__(256) void k_gates(
    const float* __restrict__ feat, const float* __restrict__ pos,
    const float* __restrict__ Wg, const float* __restrict__ bg,
    float* __restrict__ gout) {
  const int row = blockIdx.x;  // 0..8191
  const int tid = threadIdx.x;
  const int k = tid * 4;
  float4 f4 = (k < 512) ? *(const float4*)(feat + (size_t)row * 512 + k)
                        : *(const float4*)(pos + (size_t)row * 512 + (k - 512));
  __shared__ float s[256][9];
#pragma unroll
  for (int h = 0; h < 8; ++h) {
    float4 w4 = *(const float4*)(Wg + h * 1024 + k);
    s[tid][h] = f4.x * w4.x + f4.y * w4.y + f4.z * w4.z + f4.w * w4.w;
  }
  __syncthreads();
  for (int st = 128; st > 0; st >>= 1) {
    if (tid < st) {
#pragma unroll
      for (int h = 0; h < 8; ++h) s[tid][h] += s[tid + st][h];
    }
    __syncthreads();
  }
  if (tid == 0) {
    float lg[8];
    float m = -1e30f;
#pragma unroll
    for (int h = 0; h < 8; ++h) {
      lg[h] = s[0][h] + bg[h];
      m = fmaxf(m, lg[h]);
    }
    float l = 0.f;
#pragma unroll
    for (int h = 0; h < 8; ++h) l += __expf(lg[h] - m);
    const float lse = m + __logf(l);
#pragma unroll
    for (int h = 0; h < 8; ++h) gout[row * 8 + h] = lg[h] - lse;
  }
}

// ---------------------------------------------------------------- pass1: L[b,i,h] = log sum_{i<j<nv} exp(q.k/8)
__global__ __launch_bounds__(256) void k_pass1(
    const float* __restrict__ q, const float* __restrict__ kk,
    const int* __restrict__ nvp, float* __restrict__ L) {
  const int it = blockIdx.x;  // 0..15
  const int h = blockIdx.y;   // 0..7
  const int b = blockIdx.z;   // 0..7
  const int nv = nvp[b];
  const int i0 = it * 64;
  const int tid = threadIdx.x;
  const int tx = tid & 15, ty = tid >> 4;
  __shared__ float Qs[64][68];
  __shared__ float Ks[64][68];
  __shared__ float red[64][17];

  load_tile64(Qs, q + ((size_t)(b * T + i0) * NH + h) * CHD, tid);

  float lsum[4] = {0.f, 0.f, 0.f, 0.f};
  for (int jt = it; jt * 64 < nv; ++jt) {
    const int j0 = jt * 64;
    __syncthreads();
    load_tile64(Ks, kk + ((size_t)(b * T + j0) * NH + h) * CHD, tid);
    __syncthreads();
    float acc[4][4] = {};
#pragma unroll 8
    for (int c = 0; c < 64; ++c) {
      float4 a = *(const float4*)&Qs[c][ty * 4];
      float4 b4 = *(const float4*)&Ks[c][tx * 4];
      fma16(acc, a, b4);
    }
#pragma unroll
    for (int r = 0; r < 4; ++r) {
      const int i = i0 + ty * 4 + r;
#pragma unroll
      for (int e = 0; e < 4; ++e) {
        const int j = j0 + tx * 4 + e;
        if (j > i && j < nv) lsum[r] += __expf(acc[r][e] * 0.125f);
      }
    }
  }
  __syncthreads();
#pragma unroll
  for (int r = 0; r < 4; ++r) red[ty * 4 + r][tx] = lsum[r];
  __syncthreads();
  if (tid < 64) {
    float ssum = 0.f;
#pragma unroll
    for (int x = 0; x < 16; ++x) ssum += red[tid][x];
    L[((size_t)(b * T + i0 + tid)) * NH + h] = (ssum > 0.f) ? __logf(ssum) : NEG_INF;
  }
}

// ---------------------------------------------------------------- pass2: out[b,i,j] = log sum_h exp(s - L + g)
__global__ __launch_bounds__(256) void k_pass2(
    const float* __restrict__ q, const float* __restrict__ kk,
    const float* __restrict__ g, const float* __restrict__ L,
    const int* __restrict__ nvp, float* __restrict__ out) {
  const int jt = blockIdx.x;  // 0..15
  const int it = blockIdx.y;  // 0..15
  const int b = blockIdx.z;   // 0..7
  const int nv = nvp[b];
  const int i0 = it * 64, j0 = jt * 64;
  const int tid = threadIdx.x;
  const int tx = tid & 15, ty = tid >> 4;

  if (jt < it || j0 >= nv) {  // entire tile invalid -> sentinel
    float4 v;
    v.x = v.y = v.z = v.w = SENT;
#pragma unroll
    for (int r = 0; r < 4; ++r) {
      const int i = i0 + ty * 4 + r;
      *(float4*)(out + ((size_t)b * T + i) * T + j0 + tx * 4) = v;
    }
    return;
  }

  __shared__ float Qs[64][68];
  __shared__ float Ks[64][68];
  __shared__ float wsh[8][64];  // g - L per (h, row)
  if (tid < 64) {
    const int rowg = (b * T + i0 + tid) * NH;
#pragma unroll
    for (int h = 0; h < 8; ++h) {
      const float Lv = L[rowg + h];
      wsh[h][tid] = (Lv == NEG_INF) ? NEG_INF : (g[rowg + h] - Lv);
    }
  }

  float se[4][4] = {};
  for (int h = 0; h < 8; ++h) {
    __syncthreads();
    load_tile64(Qs, q + ((size_t)(b * T + i0) * NH + h) * CHD, tid);
    load_tile64(Ks, kk + ((size_t)(b * T + j0) * NH + h) * CHD, tid);
    __syncthreads();
    float acc[4][4] = {};
#pragma unroll 8
    for (int c = 0; c < 64; ++c) {
      float4 a = *(const float4*)&Qs[c][ty * 4];
      float4 b4 = *(const float4*)&Ks[c][tx * 4];
      fma16(acc, a, b4);
    }
#pragma unroll
    for (int r = 0; r < 4; ++r) {
      const float wv = wsh[h][ty * 4 + r];
#pragma unroll
      for (int e = 0; e < 4; ++e) se[r][e] += __expf(acc[r][e] * 0.125f + wv);
    }
  }

#pragma unroll
  for (int r = 0; r < 4; ++r) {
    const int i = i0 + ty * 4 + r;
    const int jb = j0 + tx * 4;
    float4 v;
    // clamp: no -inf/nan may ever reach d_out
    v.x = (jb + 0 > i && jb + 0 < nv) ? fmaxf(__logf(se[r][0]), SENT) : SENT;
    v.y = (jb + 1 > i && jb + 1 < nv) ? fmaxf(__logf(se[r][1]), SENT) : SENT;
    v.z = (jb + 2 > i && jb + 2 < nv) ? fmaxf(__logf(se[r][2]), SENT) : SENT;
    v.w = (jb + 3 > i && jb + 3 < nv) ? fmaxf(__logf(se[r][3]), SENT) : SENT;
    *(float4*)(out + ((size_t)b * T + i) * T + jb) = v;
  }
}

// ---------------------------------------------------------------- launch
extern "C" void kernel_launch(void* const* d_in, const int* in_sizes, int n_in,
                              void* d_out, int out_size, void* d_ws, size_t ws_size,
                              hipStream_t stream) {
  (void)in_sizes; (void)n_in; (void)out_size; (void)ws_size;
  const float* feat = (const float*)d_in[0];
  const float* pos  = (const float*)d_in[1];
  const int* tokens = (const int*)d_in[2];
  const float* Wq = (const float*)d_in[3];
  const float* bq = (const float*)d_in[4];
  const float* Wk = (const float*)d_in[5];
  const float* bk = (const float*)d_in[6];
  const float* Wg = (const float*)d_in[7];
  const float* bg = (const float*)d_in[8];
  float* out = (float*)d_out;

  float* qbuf = (float*)d_ws;               // 8192*512 floats
  float* kbuf = qbuf + (size_t)NROW * DM;   // 8192*512
  float* gbuf = kbuf + (size_t)NROW * DM;   // 8192*8
  float* Lbuf = gbuf + (size_t)NROW * NH;   // 8192*8
  int* nv = (int*)(Lbuf + (size_t)NROW * NH);

  k_nvalid<<<dim3(BATCH), dim3(256), 0, stream>>>(tokens, nv);
  k_qk_gemm<<<dim3(16, 128), dim3(256), 0, stream>>>(feat, pos, Wq, bq, Wk, bk, qbuf, kbuf);
  k_gates<<<dim3(NROW), dim3(256), 0, stream>>>(feat, pos, Wg, bg, gbuf);
  k_pass1<<<dim3(16, NH, BATCH), dim3(256), 0, stream>>>(qbuf, kbuf, nv, Lbuf);
  k_pass2<<<dim3(16, 16, BATCH), dim3(256), 0, stream>>>(qbuf, kbuf, gbuf, Lbuf, nv, out);
}

// Round 3
// 224.687 us; speedup vs baseline: 2.7651x; 2.7651x over previous
//
#include <hip/hip_runtime.h>
#include <math.h>

#define BATCH 8
#define T 1024
#define DM 512
#define NH 8
#define CHD 64
#define NROW 8192
#define NEG_INF (-INFINITY)
#define SENT (-1.0e30f)

typedef __attribute__((ext_vector_type(8))) short short8;   // 8 bf16 (4 VGPRs)
typedef __attribute__((ext_vector_type(4))) float f32x4;

// fp32 -> bf16 (RNE)
__device__ __forceinline__ ushort f2bf(float x) {
  uint u = __float_as_uint(x);
  return (ushort)((u + 0x7FFFu + ((u >> 16) & 1u)) >> 16);
}
__device__ __forceinline__ uint pack2(float a, float b) {
  return (uint)f2bf(a) | ((uint)f2bf(b) << 16);
}

// ---------------------------------------------------------------- n_valid
__global__ __launch_bounds__(256) void k_nvalid(const int* __restrict__ tokens,
                                                int* __restrict__ nv) {
  int b = blockIdx.x, t = threadIdx.x;
  int cnt = 0;
  for (int i = t; i < T; i += 256) cnt += (tokens[b * T + i] != 0) ? 1 : 0;
  __shared__ int s[256];
  s[t] = cnt;
  __syncthreads();
  for (int st = 128; st > 0; st >>= 1) {
    if (t < st) s[t] += s[t + st];
    __syncthreads();
  }
  if (t == 0) nv[b] = s[0];
}

// ---------------------------------------------------------------- W -> bf16 concat
// Wbf[n][k], n<512 -> Wq[n], else Wk[n-512]; 8 elems per thread
__global__ __launch_bounds__(256) void k_prep_w(const float* __restrict__ Wq,
                                                const float* __restrict__ Wk,
                                                ushort* __restrict__ Wbf) {
  const int gid = blockIdx.x * 256 + threadIdx.x;  // 0..131071
  const int e0 = gid * 8;
  const int n = e0 >> 10, k = e0 & 1023;
  const float* src = (n < 512) ? (Wq + (size_t)n * 1024 + k)
                               : (Wk + (size_t)(n - 512) * 1024 + k);
  float4 a = *(const float4*)src;
  float4 b = *(const float4*)(src + 4);
  uint4 o;
  o.x = pack2(a.x, a.y); o.y = pack2(a.z, a.w);
  o.z = pack2(b.x, b.y); o.w = pack2(b.z, b.w);
  *(uint4*)(Wbf + (size_t)n * 1024 + k) = o;
}

// ---------------------------------------------------------------- fused q/k GEMM (bf16 MFMA)
// C[8192 x 1024] = f @ W^T + bias; f = concat(feat,pos) converted on the fly.
// col<512 -> qbuf bf16, else kbuf bf16. Tiles: 128x128, BK=64.
__global__ __launch_bounds__(256) void k_gemm(
    const float* __restrict__ feat, const float* __restrict__ pos,
    const ushort* __restrict__ Wbf,
    const float* __restrict__ bq, const float* __restrict__ bk,
    ushort* __restrict__ qbuf, ushort* __restrict__ kbuf) {
  const int n0 = blockIdx.x * 128;   // 0..896
  const int m0 = blockIdx.y * 128;   // 0..8064
  const int tid = threadIdx.x;
  const int w = tid >> 6, l = tid & 63;
  const int lo = l & 15, quad = l >> 4;
  const int wm0 = (w >> 1) * 64, wn0 = (w & 1) * 64;

  __shared__ ushort As[128][72];  // stride 144B = 9*16B: b128-aligned, 2-way banks (free)
  __shared__ ushort Bs[128][72];

  f32x4 acc[4][4];
#pragma unroll
  for (int i = 0; i < 4; ++i)
#pragma unroll
    for (int j = 0; j < 4; ++j) acc[i][j] = (f32x4){0.f, 0.f, 0.f, 0.f};

  for (int k0 = 0; k0 < 1024; k0 += 64) {
    __syncthreads();
    // stage A (convert fp32->bf16) : 128 rows x 8 chunks of 8
#pragma unroll
    for (int u = 0; u < 4; ++u) {
      const int cid = tid + 256 * u;
      const int r = cid >> 3, c = (cid & 7) * 8;
      const int gk = k0 + c;
      const float* src = (gk < 512) ? (feat + (size_t)(m0 + r) * 512 + gk)
                                    : (pos + (size_t)(m0 + r) * 512 + (gk - 512));
      float4 a = *(const float4*)src;
      float4 b = *(const float4*)(src + 4);
      uint4 o;
      o.x = pack2(a.x, a.y); o.y = pack2(a.z, a.w);
      o.z = pack2(b.x, b.y); o.w = pack2(b.z, b.w);
      *(uint4*)&As[r][c] = o;
    }
    // stage B (already bf16): 128 rows x 8 chunks
#pragma unroll
    for (int u = 0; u < 4; ++u) {
      const int cid = tid + 256 * u;
      const int r = cid >> 3, c = (cid & 7) * 8;
      *(uint4*)&Bs[r][c] = *(const uint4*)(Wbf + (size_t)(n0 + r) * 1024 + k0 + c);
    }
    __syncthreads();
#pragma unroll
    for (int kk = 0; kk < 2; ++kk) {
      short8 af[4], bf[4];
#pragma unroll
      for (int mi = 0; mi < 4; ++mi)
        af[mi] = *(const short8*)&As[wm0 + mi * 16 + lo][kk * 32 + quad * 8];
#pragma unroll
      for (int ni = 0; ni < 4; ++ni)
        bf[ni] = *(const short8*)&Bs[wn0 + ni * 16 + lo][kk * 32 + quad * 8];
#pragma unroll
      for (int mi = 0; mi < 4; ++mi)
#pragma unroll
        for (int ni = 0; ni < 4; ++ni)
          acc[mi][ni] = __builtin_amdgcn_mfma_f32_16x16x32_bf16(af[mi], bf[ni], acc[mi][ni], 0, 0, 0);
    }
  }

  // epilogue: bias + bf16 store
  float bv[4];
#pragma unroll
  for (int ni = 0; ni < 4; ++ni) {
    const int gn = n0 + wn0 + ni * 16 + lo;
    bv[ni] = (gn < 512) ? bq[gn] : bk[gn - 512];
  }
#pragma unroll
  for (int mi = 0; mi < 4; ++mi)
#pragma unroll
    for (int ni = 0; ni < 4; ++ni) {
      const int gn = n0 + wn0 + ni * 16 + lo;
      ushort* dst = (gn < 512) ? (qbuf + gn) : (kbuf + gn - 512);
#pragma unroll
      for (int r = 0; r < 4; ++r) {
        const int m = m0 + wm0 + mi * 16 + quad * 4 + r;
        dst[(size_t)m * 512] = f2bf(acc[mi][ni][r] + bv[ni]);
      }
    }
}

// ---------------------------------------------------------------- gates (wave per row)
__global__ __launch_bounds__(64) void k_gates(
    const float* __restrict__ feat, const float* __restrict__ pos,
    const float* __restrict__ Wg, const float* __restrict__ bg,
    float* __restrict__ gout) {
  const int row = blockIdx.x;
  const int l = threadIdx.x;
  const int c0 = l * 16;
  const float* src = (c0 < 512) ? (feat + (size_t)row * 512 + c0)
                                : (pos + (size_t)row * 512 + (c0 - 512));
  float4 f0 = *(const float4*)(src + 0);
  float4 f1 = *(const float4*)(src + 4);
  float4 f2 = *(const float4*)(src + 8);
  float4 f3 = *(const float4*)(src + 12);
  float s[8];
#pragma unroll
  for (int h = 0; h < 8; ++h) {
    const float* wg = Wg + (size_t)h * 1024 + c0;
    float4 w0 = *(const float4*)(wg + 0);
    float4 w1 = *(const float4*)(wg + 4);
    float4 w2 = *(const float4*)(wg + 8);
    float4 w3 = *(const float4*)(wg + 12);
    s[h] = f0.x * w0.x + f0.y * w0.y + f0.z * w0.z + f0.w * w0.w
         + f1.x * w1.x + f1.y * w1.y + f1.z * w1.z + f1.w * w1.w
         + f2.x * w2.x + f2.y * w2.y + f2.z * w2.z + f2.w * w2.w
         + f3.x * w3.x + f3.y * w3.y + f3.z * w3.z + f3.w * w3.w;
  }
#pragma unroll
  for (int m = 1; m < 64; m <<= 1)
#pragma unroll
    for (int h = 0; h < 8; ++h) s[h] += __shfl_xor(s[h], m, 64);
  if (l == 0) {
    float lg[8], mx = -1e30f;
#pragma unroll
    for (int h = 0; h < 8; ++h) { lg[h] = s[h] + bg[h]; mx = fmaxf(mx, lg[h]); }
    float sum = 0.f;
#pragma unroll
    for (int h = 0; h < 8; ++h) sum += __expf(lg[h] - mx);
    const float lse = mx + __logf(sum);
#pragma unroll
    for (int h = 0; h < 8; ++h) gout[(size_t)row * 8 + h] = lg[h] - lse;
  }
}

// ---------------------------------------------------------------- pass1: L[b,i,h] (bf16 MFMA)
__global__ __launch_bounds__(256) void k_pass1(
    const ushort* __restrict__ q, const ushort* __restrict__ kk,
    const int* __restrict__ nvp, float* __restrict__ L) {
  const int it = blockIdx.x, h = blockIdx.y, b = blockIdx.z;
  const int nv = nvp[b];
  const int i0 = it * 64;
  const int tid = threadIdx.x;
  const int w = tid >> 6, l = tid & 63;
  const int lo = l & 15, quad = l >> 4;

  __shared__ ushort Qs[64][72];
  __shared__ ushort Ks[64][72];

  // stage Q tile (64 x 64) for head h
#pragma unroll
  for (int u = 0; u < 2; ++u) {
    const int cid = tid + 256 * u;
    const int r = cid >> 3, c = (cid & 7) * 8;
    *(uint4*)&Qs[r][c] = *(const uint4*)(q + ((size_t)(b * T + i0 + r) * 512) + h * 64 + c);
  }
  __syncthreads();
  short8 a0 = *(const short8*)&Qs[w * 16 + lo][quad * 8];
  short8 a1 = *(const short8*)&Qs[w * 16 + lo][32 + quad * 8];

  float lsum[4] = {0.f, 0.f, 0.f, 0.f};
  for (int jt = it; jt * 64 < nv; ++jt) {
    const int j0 = jt * 64;
    __syncthreads();
#pragma unroll
    for (int u = 0; u < 2; ++u) {
      const int cid = tid + 256 * u;
      const int r = cid >> 3, c = (cid & 7) * 8;
      *(uint4*)&Ks[r][c] = *(const uint4*)(kk + ((size_t)(b * T + j0 + r) * 512) + h * 64 + c);
    }
    __syncthreads();
#pragma unroll
    for (int ni = 0; ni < 4; ++ni) {
      short8 b0 = *(const short8*)&Ks[ni * 16 + lo][quad * 8];
      short8 b1 = *(const short8*)&Ks[ni * 16 + lo][32 + quad * 8];
      f32x4 acc = (f32x4){0.f, 0.f, 0.f, 0.f};
      acc = __builtin_amdgcn_mfma_f32_16x16x32_bf16(a0, b0, acc, 0, 0, 0);
      acc = __builtin_amdgcn_mfma_f32_16x16x32_bf16(a1, b1, acc, 0, 0, 0);
      const int j = j0 + ni * 16 + lo;
#pragma unroll
      for (int r = 0; r < 4; ++r) {
        const int i = i0 + w * 16 + quad * 4 + r;
        if (j > i && j < nv) lsum[r] += __expf(acc[r] * 0.125f);
      }
    }
  }
#pragma unroll
  for (int m = 1; m < 16; m <<= 1)
#pragma unroll
    for (int r = 0; r < 4; ++r) lsum[r] += __shfl_xor(lsum[r], m, 64);
  if (lo == 0) {
#pragma unroll
    for (int r = 0; r < 4; ++r) {
      const int i = i0 + w * 16 + quad * 4 + r;
      L[((size_t)(b * T + i)) * 8 + h] = (lsum[r] > 0.f) ? __logf(lsum[r]) : NEG_INF;
    }
  }
}

// ---------------------------------------------------------------- pass2 (bf16 MFMA)
__global__ __launch_bounds__(256) void k_pass2(
    const ushort* __restrict__ q, const ushort* __restrict__ kk,
    const float* __restrict__ g, const float* __restrict__ L,
    const int* __restrict__ nvp, float* __restrict__ out) {
  const int jt = blockIdx.x, it = blockIdx.y, b = blockIdx.z;
  const int nv = nvp[b];
  const int i0 = it * 64, j0 = jt * 64;
  const int tid = threadIdx.x;

  if (jt < it || j0 >= nv) {
    const int r0 = tid >> 4, c0 = (tid & 15) * 4;
    float4 v; v.x = v.y = v.z = v.w = SENT;
#pragma unroll
    for (int u = 0; u < 4; ++u)
      *(float4*)(out + ((size_t)(b * T + i0 + r0 + u * 16)) * T + j0 + c0) = v;
    return;
  }

  const int w = tid >> 6, l = tid & 63;
  const int lo = l & 15, quad = l >> 4;

  __shared__ ushort Qs[64][72];
  __shared__ ushort Ks[64][72];
  __shared__ float wsh[8][64];

  if (tid < 64) {
    const size_t rowg = ((size_t)(b * T + i0 + tid)) * 8;
#pragma unroll
    for (int h = 0; h < 8; ++h) {
      const float Lv = L[rowg + h];
      wsh[h][tid] = (Lv == NEG_INF) ? NEG_INF : (g[rowg + h] - Lv);
    }
  }

  float se[4][4];  // [ni][r]
#pragma unroll
  for (int a = 0; a < 4; ++a)
#pragma unroll
    for (int c = 0; c < 4; ++c) se[a][c] = 0.f;

  for (int h = 0; h < 8; ++h) {
    __syncthreads();
#pragma unroll
    for (int u = 0; u < 4; ++u) {
      const int cid = tid + 256 * u;  // 0..511 Q, 512..1023 K
      const int r = (cid & 511) >> 3, c = (cid & 7) * 8;
      if (cid < 512)
        *(uint4*)&Qs[r][c] = *(const uint4*)(q + ((size_t)(b * T + i0 + r) * 512) + h * 64 + c);
      else
        *(uint4*)&Ks[r][c] = *(const uint4*)(kk + ((size_t)(b * T + j0 + r) * 512) + h * 64 + c);
    }
    __syncthreads();
    short8 a0 = *(const short8*)&Qs[w * 16 + lo][quad * 8];
    short8 a1 = *(const short8*)&Qs[w * 16 + lo][32 + quad * 8];
    float wv[4];
#pragma unroll
    for (int r = 0; r < 4; ++r) wv[r] = wsh[h][w * 16 + quad * 4 + r];
#pragma unroll
    for (int ni = 0; ni < 4; ++ni) {
      short8 b0 = *(const short8*)&Ks[ni * 16 + lo][quad * 8];
      short8 b1 = *(const short8*)&Ks[ni * 16 + lo][32 + quad * 8];
      f32x4 acc = (f32x4){0.f, 0.f, 0.f, 0.f};
      acc = __builtin_amdgcn_mfma_f32_16x16x32_bf16(a0, b0, acc, 0, 0, 0);
      acc = __builtin_amdgcn_mfma_f32_16x16x32_bf16(a1, b1, acc, 0, 0, 0);
#pragma unroll
      for (int r = 0; r < 4; ++r) se[ni][r] += __expf(acc[r] * 0.125f + wv[r]);
    }
  }

#pragma unroll
  for (int ni = 0; ni < 4; ++ni) {
    const int j = j0 + ni * 16 + lo;
#pragma unroll
    for (int r = 0; r < 4; ++r) {
      const int i = i0 + w * 16 + quad * 4 + r;
      out[((size_t)(b * T + i)) * T + j] =
          (j > i && j < nv) ? fmaxf(__logf(se[ni][r]), SENT) : SENT;
    }
  }
}

// ---------------------------------------------------------------- launch
extern "C" void kernel_launch(void* const* d_in, const int* in_sizes, int n_in,
                              void* d_out, int out_size, void* d_ws, size_t ws_size,
                              hipStream_t stream) {
  (void)in_sizes; (void)n_in; (void)out_size; (void)ws_size;
  const float* feat = (const float*)d_in[0];
  const float* pos  = (const float*)d_in[1];
  const int* tokens = (const int*)d_in[2];
  const float* Wq = (const float*)d_in[3];
  const float* bq = (const float*)d_in[4];
  const float* Wk = (const float*)d_in[5];
  const float* bk = (const float*)d_in[6];
  const float* Wg = (const float*)d_in[7];
  const float* bg = (const float*)d_in[8];
  float* out = (float*)d_out;

  // workspace layout (bytes): qbuf 8.4M | kbuf 8.4M | Wbf 2M | gbuf 256K | Lbuf 256K | nv
  ushort* qbuf = (ushort*)d_ws;                         // 8192*512 bf16
  ushort* kbuf = qbuf + (size_t)NROW * 512;             // 8192*512 bf16
  ushort* Wbf  = kbuf + (size_t)NROW * 512;             // 1024*1024 bf16
  float*  gbuf = (float*)(Wbf + (size_t)1024 * 1024);   // 8192*8 f32
  float*  Lbuf = gbuf + (size_t)NROW * NH;              // 8192*8 f32
  int*    nv   = (int*)(Lbuf + (size_t)NROW * NH);

  k_nvalid<<<dim3(BATCH), dim3(256), 0, stream>>>(tokens, nv);
  k_prep_w<<<dim3(512), dim3(256), 0, stream>>>(Wq, Wk, Wbf);
  k_gemm<<<dim3(8, 64), dim3(256), 0, stream>>>(feat, pos, Wbf, bq, bk, qbuf, kbuf);
  k_gates<<<dim3(NROW), dim3(64), 0, stream>>>(feat, pos, Wg, bg, gbuf);
  k_pass1<<<dim3(16, NH, BATCH), dim3(256), 0, stream>>>(qbuf, kbuf, nv, Lbuf);
  k_pass2<<<dim3(16, 16, BATCH), dim3(256), 0, stream>>>(qbuf, kbuf, gbuf, Lbuf, nv, out);
}